// Round 1
// baseline (443.624 us; speedup 1.0000x reference)
//
#include <hip/hip_runtime.h>
#include <math.h>

static constexpr int B_ = 4;
static constexpr int L_ = 1024;
static constexpr int S_ = 1024;
static constexpr int DMODEL = 512;
static constexpr int NH = 8;
static constexpr int DH = 64;
static constexpr int NBH = 32;   // B_*NH

// ---------------------------------------------------------------------------
// Generic 64x64 f32 NN GEMM: C = A(MxK) @ B(KxN), row-major A and B.
// BM=BN=64, BK=16, 256 threads, 4x4 micro-tile per thread.
// MODE 0: store as (B,H,D,L)  [q^T / k^T layout for the TN scores GEMM]
// MODE 1: store as (B,H,S,D)  [v layout for PV]
// MODE 2: plain row-major MxN [final output]
// ---------------------------------------------------------------------------
template<int MODE>
__global__ __launch_bounds__(256)
void gemm_nn_kernel(const float* __restrict__ A, const float* __restrict__ Bm,
                    float* __restrict__ C, int M, int N, int K) {
  __shared__ float As[16][68];   // [k][m], pitch 68 -> 16B-aligned float4 rows
  __shared__ float Bs[16][64];   // [k][n]
  const int tid = threadIdx.x;
  const int tx = tid & 15, ty = tid >> 4;
  const int mBase = blockIdx.y * 64;
  const int nBase = blockIdx.x * 64;
  const int arow = tid >> 2;          // 0..63
  const int acol = (tid & 3) << 2;    // 0,4,8,12
  const int brow = tid >> 4;          // 0..15
  const int bcol = (tid & 15) << 2;   // 0..60
  const float* Ap = A + (size_t)(mBase + arow) * K + acol;
  const float* Bp = Bm + (size_t)brow * N + nBase + bcol;
  float acc[4][4] = {};
  for (int k0 = 0; k0 < K; k0 += 16) {
    const float4 av = *(const float4*)(Ap + k0);
    const float4 bv = *(const float4*)(Bp + (size_t)k0 * N);
    __syncthreads();
    As[acol + 0][arow] = av.x;
    As[acol + 1][arow] = av.y;
    As[acol + 2][arow] = av.z;
    As[acol + 3][arow] = av.w;
    *(float4*)&Bs[brow][bcol] = bv;
    __syncthreads();
#pragma unroll
    for (int kk = 0; kk < 16; ++kk) {
      const float4 a4 = *(const float4*)&As[kk][ty << 2];
      const float4 b4 = *(const float4*)&Bs[kk][tx << 2];
      const float aa[4] = {a4.x, a4.y, a4.z, a4.w};
      const float bb[4] = {b4.x, b4.y, b4.z, b4.w};
#pragma unroll
      for (int ii = 0; ii < 4; ++ii)
#pragma unroll
        for (int jj = 0; jj < 4; ++jj)
          acc[ii][jj] = fmaf(aa[ii], bb[jj], acc[ii][jj]);
    }
  }

  const int m0 = mBase + (ty << 2);
  if (MODE == 0) {
    // (B,H,D,L): contiguous in l == m. 64-row tile never crosses a b boundary.
    const int bb2 = m0 >> 10;
    const int l0 = m0 & 1023;
#pragma unroll
    for (int jj = 0; jj < 4; ++jj) {
      const int n = nBase + (tx << 2) + jj;
      const int hh = n >> 6, d = n & 63;
      float4 v4 = make_float4(acc[0][jj], acc[1][jj], acc[2][jj], acc[3][jj]);
      *(float4*)&C[(size_t)((bb2 * NH + hh) * DH + d) * L_ + l0] = v4;
    }
  } else if (MODE == 1) {
    // (B,H,S,D): contiguous in d == n within a head (tx*4 never crosses 64)
    const int bb2 = m0 >> 10;
    const int n0 = nBase + (tx << 2);
    const int hh = n0 >> 6, d0 = n0 & 63;
#pragma unroll
    for (int ii = 0; ii < 4; ++ii) {
      const int s = (m0 + ii) & 1023;
      float4 v4 = make_float4(acc[ii][0], acc[ii][1], acc[ii][2], acc[ii][3]);
      *(float4*)&C[(size_t)((bb2 * NH + hh) * S_ + s) * DH + d0] = v4;
    }
  } else {
#pragma unroll
    for (int ii = 0; ii < 4; ++ii) {
      const int m = m0 + ii;
      float4 v4 = make_float4(acc[ii][0], acc[ii][1], acc[ii][2], acc[ii][3]);
      *(float4*)&C[(size_t)m * N + nBase + (tx << 2)] = v4;
    }
  }
}

// ---------------------------------------------------------------------------
// Scores: per bh, C[l][s] = (1/8) * sum_d qT[d][l] * kT[d][s]   (TN GEMM, K=64)
// qT,kT are (B,H,D,L). Direct LDS staging, no transpose, fully coalesced.
// ---------------------------------------------------------------------------
__global__ __launch_bounds__(256)
void scores_kernel(const float* __restrict__ qT, const float* __restrict__ kT,
                   float* __restrict__ Sc) {
  __shared__ float As[16][64];
  __shared__ float Bs[16][64];
  const int z = blockIdx.z;
  const float* Ap = qT + (size_t)z * DH * L_;
  const float* Bp = kT + (size_t)z * DH * S_;
  float* Cp = Sc + (size_t)z * L_ * S_;
  const int tid = threadIdx.x;
  const int tx = tid & 15, ty = tid >> 4;
  const int mBase = blockIdx.y * 64;
  const int nBase = blockIdx.x * 64;
  const int lrow = tid >> 4;          // 0..15 (k row)
  const int lcol = (tid & 15) << 2;   // 0..60
  float acc[4][4] = {};
  for (int k0 = 0; k0 < DH; k0 += 16) {
    const float4 av = *(const float4*)(Ap + (size_t)(k0 + lrow) * L_ + mBase + lcol);
    const float4 bv = *(const float4*)(Bp + (size_t)(k0 + lrow) * S_ + nBase + lcol);
    __syncthreads();
    *(float4*)&As[lrow][lcol] = av;
    *(float4*)&Bs[lrow][lcol] = bv;
    __syncthreads();
#pragma unroll
    for (int kk = 0; kk < 16; ++kk) {
      const float4 a4 = *(const float4*)&As[kk][ty << 2];
      const float4 b4 = *(const float4*)&Bs[kk][tx << 2];
      const float aa[4] = {a4.x, a4.y, a4.z, a4.w};
      const float bb[4] = {b4.x, b4.y, b4.z, b4.w};
#pragma unroll
      for (int ii = 0; ii < 4; ++ii)
#pragma unroll
        for (int jj = 0; jj < 4; ++jj)
          acc[ii][jj] = fmaf(aa[ii], bb[jj], acc[ii][jj]);
    }
  }
#pragma unroll
  for (int ii = 0; ii < 4; ++ii) {
    const int l = mBase + (ty << 2) + ii;
    float4 v4 = make_float4(acc[ii][0] * 0.125f, acc[ii][1] * 0.125f,
                            acc[ii][2] * 0.125f, acc[ii][3] * 0.125f);
    *(float4*)&Cp[(size_t)l * S_ + nBase + (tx << 2)] = v4;
  }
}

// ---------------------------------------------------------------------------
// path_mean[i][j] = (1/32) * sum_bh Sc[bh][i][m1] * Sc[bh][m2][j]
//   m1 = floor(i + (j-i)/3) = (2i+j)/3 ;  m2 = floor(i + 2(j-i)/3) = (i+2j)/3
// (both always in [0, 1023]; integer division == floor since numerators >= 0)
// ---------------------------------------------------------------------------
__global__ __launch_bounds__(256)
void path_mean_kernel(const float* __restrict__ Sc, float* __restrict__ pm) {
  const int j = blockIdx.x * 256 + threadIdx.x;
  const int i = blockIdx.y;
  const int m1 = (2 * i + j) / 3;
  const int m2 = (i + 2 * j) / 3;
  const size_t offA = (size_t)i * S_ + m1;
  const size_t offB = (size_t)m2 * S_ + j;
  float acc = 0.f;
#pragma unroll 8
  for (int z = 0; z < NBH; ++z) {
    const size_t base = (size_t)z * L_ * S_;
    acc += Sc[base + offA] * Sc[base + offB];
  }
  pm[(size_t)i * S_ + j] = acc * (1.f / 32.f);
}

// ---------------------------------------------------------------------------
// Masked softmax, in place over the scores region (which becomes attn).
// Row r = (bh, i). val[j] = |i-j|<=3 ? Sc[r][j] : pm[i][j]; softmax over j.
// ---------------------------------------------------------------------------
__global__ __launch_bounds__(256)
void softmax_kernel(float* __restrict__ Sc, const float* __restrict__ pm) {
  const int r = blockIdx.x;            // 0..32767
  const int i = r & 1023;
  float* row = Sc + (size_t)r * S_;
  const float* pmrow = pm + (size_t)i * S_;
  const int tid = threadIdx.x;
  const int j0 = tid << 2;
  const float4 sv = *(const float4*)(row + j0);
  const float4 pv = *(const float4*)(pmrow + j0);
  float vals[4] = {sv.x, sv.y, sv.z, sv.w};
  const float pvals[4] = {pv.x, pv.y, pv.z, pv.w};
  float mx = -1e30f;
#pragma unroll
  for (int u = 0; u < 4; ++u) {
    const int j = j0 + u;
    const int diff = i - j;
    const bool near = (diff <= 3) && (diff >= -3);
    vals[u] = near ? vals[u] : pvals[u];
    mx = fmaxf(mx, vals[u]);
  }
  __shared__ float redm[4];
  __shared__ float reds[4];
  const int lane = tid & 63, wid = tid >> 6;
#pragma unroll
  for (int off = 32; off >= 1; off >>= 1) mx = fmaxf(mx, __shfl_xor(mx, off));
  if (lane == 0) redm[wid] = mx;
  __syncthreads();
  mx = fmaxf(fmaxf(redm[0], redm[1]), fmaxf(redm[2], redm[3]));
  float sum = 0.f;
#pragma unroll
  for (int u = 0; u < 4; ++u) {
    vals[u] = __expf(vals[u] - mx);
    sum += vals[u];
  }
#pragma unroll
  for (int off = 32; off >= 1; off >>= 1) sum += __shfl_xor(sum, off);
  if (lane == 0) reds[wid] = sum;
  __syncthreads();
  sum = reds[0] + reds[1] + reds[2] + reds[3];
  const float inv = 1.f / sum;
  float4 o = make_float4(vals[0] * inv, vals[1] * inv, vals[2] * inv, vals[3] * inv);
  *(float4*)(row + j0) = o;
}

// ---------------------------------------------------------------------------
// PV: per bh, out1[b][l][h*64+d] = sum_s attn[bh][l][s] * v[bh][s][d]
// NN GEMM, BM=64, BN=64(=DH full), BK=16; A transposed into LDS on store.
// ---------------------------------------------------------------------------
__global__ __launch_bounds__(256)
void gemm_pv_kernel(const float* __restrict__ attn, const float* __restrict__ v,
                    float* __restrict__ out1) {
  __shared__ float As[16][68];
  __shared__ float Bs[16][64];
  const int z = blockIdx.z;
  const int bb = z >> 3, hh = z & 7;
  const float* Ap = attn + (size_t)z * L_ * S_;
  const float* Bp = v + (size_t)z * S_ * DH;
  const int tid = threadIdx.x;
  const int tx = tid & 15, ty = tid >> 4;
  const int mBase = blockIdx.y * 64;
  const int arow = tid >> 2;
  const int acol = (tid & 3) << 2;
  const int brow = tid >> 4;
  const int bcol = (tid & 15) << 2;
  float acc[4][4] = {};
  for (int k0 = 0; k0 < S_; k0 += 16) {
    const float4 av = *(const float4*)(Ap + (size_t)(mBase + arow) * S_ + k0 + acol);
    const float4 bv = *(const float4*)(Bp + (size_t)(k0 + brow) * DH + bcol);
    __syncthreads();
    As[acol + 0][arow] = av.x;
    As[acol + 1][arow] = av.y;
    As[acol + 2][arow] = av.z;
    As[acol + 3][arow] = av.w;
    *(float4*)&Bs[brow][bcol] = bv;
    __syncthreads();
#pragma unroll
    for (int kk = 0; kk < 16; ++kk) {
      const float4 a4 = *(const float4*)&As[kk][ty << 2];
      const float4 b4 = *(const float4*)&Bs[kk][tx << 2];
      const float aa[4] = {a4.x, a4.y, a4.z, a4.w};
      const float bb4[4] = {b4.x, b4.y, b4.z, b4.w};
#pragma unroll
      for (int ii = 0; ii < 4; ++ii)
#pragma unroll
        for (int jj = 0; jj < 4; ++jj)
          acc[ii][jj] = fmaf(aa[ii], bb4[jj], acc[ii][jj]);
    }
  }
#pragma unroll
  for (int ii = 0; ii < 4; ++ii) {
    const int l = mBase + (ty << 2) + ii;
    float4 v4 = make_float4(acc[ii][0], acc[ii][1], acc[ii][2], acc[ii][3]);
    *(float4*)&out1[(size_t)(bb * L_ + l) * DMODEL + hh * DH + (tx << 2)] = v4;
  }
}

// ---------------------------------------------------------------------------
extern "C" void kernel_launch(void* const* d_in, const int* in_sizes, int n_in,
                              void* d_out, int out_size, void* d_ws, size_t ws_size,
                              hipStream_t stream) {
  const float* queries = (const float*)d_in[0];
  const float* keys    = (const float*)d_in[1];
  const float* values  = (const float*)d_in[2];
  const float* Wq      = (const float*)d_in[3];
  const float* Wk      = (const float*)d_in[4];
  const float* Wv      = (const float*)d_in[5];
  const float* Wo      = (const float*)d_in[6];

  float* out  = (float*)d_out;                          // (B,L,512)
  float* attn = out + (size_t)B_ * L_ * DMODEL;         // (B,H,L,S) - also scores scratch

  float* ws   = (float*)d_ws;
  float* qT   = ws;                 // (B,H,D,L)  2,097,152 f
  float* kT   = qT + 2097152;       // (B,H,D,S)  2,097,152 f
  float* vS   = kT + 2097152;       // (B,H,S,D)  2,097,152 f
  float* out1 = vS + 2097152;       // (B,L,512)  2,097,152 f
  float* pm   = out1 + 2097152;     // (L,S)      1,048,576 f   total ~36 MB

  const dim3 blk(256);

  // 1) projections
  const dim3 gProj(DMODEL / 64, (B_ * L_) / 64);        // (8, 64)
  hipLaunchKernelGGL((gemm_nn_kernel<0>), gProj, blk, 0, stream,
                     queries, Wq, qT, B_ * L_, DMODEL, DMODEL);
  hipLaunchKernelGGL((gemm_nn_kernel<0>), gProj, blk, 0, stream,
                     keys, Wk, kT, B_ * L_, DMODEL, DMODEL);
  hipLaunchKernelGGL((gemm_nn_kernel<1>), gProj, blk, 0, stream,
                     values, Wv, vS, B_ * L_, DMODEL, DMODEL);

  // 2) scores = q k^T / 8   (written into the attn region of d_out)
  const dim3 gSc(S_ / 64, L_ / 64, NBH);                // (16,16,32)
  hipLaunchKernelGGL(scores_kernel, gSc, blk, 0, stream, qT, kT, attn);

  // 3) path_mean from raw scores
  const dim3 gPm(S_ / 256, L_);                         // (4,1024)
  hipLaunchKernelGGL(path_mean_kernel, gPm, blk, 0, stream, attn, pm);

  // 4) masked softmax in place -> attn
  const dim3 gSm(NBH * L_);                             // 32768 rows
  hipLaunchKernelGGL(softmax_kernel, gSm, blk, 0, stream, attn, pm);

  // 5) PV -> out1 (B,L,512)
  const dim3 gPv(1, L_ / 64, NBH);
  hipLaunchKernelGGL(gemm_pv_kernel, gPv, blk, 0, stream, attn, vS, out1);

  // 6) out = out1 @ W_o
  const dim3 gO(DMODEL / 64, (B_ * L_) / 64);
  hipLaunchKernelGGL((gemm_nn_kernel<2>), gO, blk, 0, stream,
                     out1, Wo, out, B_ * L_, DMODEL, DMODEL);
}

// Round 2
// 366.186 us; speedup vs baseline: 1.2115x; 1.2115x over previous
//
#include <hip/hip_runtime.h>
#include <math.h>

static constexpr int B_ = 4;
static constexpr int L_ = 1024;
static constexpr int S_ = 1024;
static constexpr int DMODEL = 512;
static constexpr int NH = 8;
static constexpr int DH = 64;
static constexpr int NBH = 32;   // B_*NH

// ---------------------------------------------------------------------------
// Generic 64x64 f32 NN GEMM: C = A(MxK) @ B(KxN), row-major A and B.
// BM=BN=64, BK=16, 256 threads, 4x4 micro-tile per thread.
// MODE 0: store as (B,H,D,L)  [q^T / k^T layout for the TN scores GEMM]
// MODE 1: store as (B,H,S,D)  [v layout for PV]
// MODE 2: plain row-major MxN [final output]
// ---------------------------------------------------------------------------
template<int MODE>
__global__ __launch_bounds__(256)
void gemm_nn_kernel(const float* __restrict__ A, const float* __restrict__ Bm,
                    float* __restrict__ C, int M, int N, int K) {
  __shared__ float As[16][68];   // [k][m], pitch 68 -> 16B-aligned float4 rows
  __shared__ float Bs[16][64];   // [k][n]
  const int tid = threadIdx.x;
  const int tx = tid & 15, ty = tid >> 4;
  const int mBase = blockIdx.y * 64;
  const int nBase = blockIdx.x * 64;
  const int arow = tid >> 2;          // 0..63
  const int acol = (tid & 3) << 2;    // 0,4,8,12
  const int brow = tid >> 4;          // 0..15
  const int bcol = (tid & 15) << 2;   // 0..60
  const float* Ap = A + (size_t)(mBase + arow) * K + acol;
  const float* Bp = Bm + (size_t)brow * N + nBase + bcol;
  float acc[4][4] = {};
  for (int k0 = 0; k0 < K; k0 += 16) {
    const float4 av = *(const float4*)(Ap + k0);
    const float4 bv = *(const float4*)(Bp + (size_t)k0 * N);
    __syncthreads();
    As[acol + 0][arow] = av.x;
    As[acol + 1][arow] = av.y;
    As[acol + 2][arow] = av.z;
    As[acol + 3][arow] = av.w;
    *(float4*)&Bs[brow][bcol] = bv;
    __syncthreads();
#pragma unroll
    for (int kk = 0; kk < 16; ++kk) {
      const float4 a4 = *(const float4*)&As[kk][ty << 2];
      const float4 b4 = *(const float4*)&Bs[kk][tx << 2];
      const float aa[4] = {a4.x, a4.y, a4.z, a4.w};
      const float bb[4] = {b4.x, b4.y, b4.z, b4.w};
#pragma unroll
      for (int ii = 0; ii < 4; ++ii)
#pragma unroll
        for (int jj = 0; jj < 4; ++jj)
          acc[ii][jj] = fmaf(aa[ii], bb[jj], acc[ii][jj]);
    }
  }

  const int m0 = mBase + (ty << 2);
  if (MODE == 0) {
    // (B,H,D,L): contiguous in l == m. 64-row tile never crosses a b boundary.
    const int bb2 = m0 >> 10;
    const int l0 = m0 & 1023;
#pragma unroll
    for (int jj = 0; jj < 4; ++jj) {
      const int n = nBase + (tx << 2) + jj;
      const int hh = n >> 6, d = n & 63;
      float4 v4 = make_float4(acc[0][jj], acc[1][jj], acc[2][jj], acc[3][jj]);
      *(float4*)&C[(size_t)((bb2 * NH + hh) * DH + d) * L_ + l0] = v4;
    }
  } else if (MODE == 1) {
    // (B,H,S,D): contiguous in d == n within a head (tx*4 never crosses 64)
    const int bb2 = m0 >> 10;
    const int n0 = nBase + (tx << 2);
    const int hh = n0 >> 6, d0 = n0 & 63;
#pragma unroll
    for (int ii = 0; ii < 4; ++ii) {
      const int s = (m0 + ii) & 1023;
      float4 v4 = make_float4(acc[ii][0], acc[ii][1], acc[ii][2], acc[ii][3]);
      *(float4*)&C[(size_t)((bb2 * NH + hh) * S_ + s) * DH + d0] = v4;
    }
  } else {
#pragma unroll
    for (int ii = 0; ii < 4; ++ii) {
      const int m = m0 + ii;
      float4 v4 = make_float4(acc[ii][0], acc[ii][1], acc[ii][2], acc[ii][3]);
      *(float4*)&C[(size_t)m * N + nBase + (tx << 2)] = v4;
    }
  }
}

// ---------------------------------------------------------------------------
// Scores: per bh, C[l][s] = (1/8) * sum_d qT[d][l] * kT[d][s]   (TN GEMM, K=64)
// qT,kT are (B,H,D,L). Direct LDS staging, no transpose, fully coalesced.
// ---------------------------------------------------------------------------
__global__ __launch_bounds__(256)
void scores_kernel(const float* __restrict__ qT, const float* __restrict__ kT,
                   float* __restrict__ Sc) {
  __shared__ float As[16][64];
  __shared__ float Bs[16][64];
  const int z = blockIdx.z;
  const float* Ap = qT + (size_t)z * DH * L_;
  const float* Bp = kT + (size_t)z * DH * S_;
  float* Cp = Sc + (size_t)z * L_ * S_;
  const int tid = threadIdx.x;
  const int tx = tid & 15, ty = tid >> 4;
  const int mBase = blockIdx.y * 64;
  const int nBase = blockIdx.x * 64;
  const int lrow = tid >> 4;          // 0..15 (k row)
  const int lcol = (tid & 15) << 2;   // 0..60
  float acc[4][4] = {};
  for (int k0 = 0; k0 < DH; k0 += 16) {
    const float4 av = *(const float4*)(Ap + (size_t)(k0 + lrow) * L_ + mBase + lcol);
    const float4 bv = *(const float4*)(Bp + (size_t)(k0 + lrow) * S_ + nBase + lcol);
    __syncthreads();
    *(float4*)&As[lrow][lcol] = av;
    *(float4*)&Bs[lrow][lcol] = bv;
    __syncthreads();
#pragma unroll
    for (int kk = 0; kk < 16; ++kk) {
      const float4 a4 = *(const float4*)&As[kk][ty << 2];
      const float4 b4 = *(const float4*)&Bs[kk][tx << 2];
      const float aa[4] = {a4.x, a4.y, a4.z, a4.w};
      const float bb[4] = {b4.x, b4.y, b4.z, b4.w};
#pragma unroll
      for (int ii = 0; ii < 4; ++ii)
#pragma unroll
        for (int jj = 0; jj < 4; ++jj)
          acc[ii][jj] = fmaf(aa[ii], bb[jj], acc[ii][jj]);
    }
  }
#pragma unroll
  for (int ii = 0; ii < 4; ++ii) {
    const int l = mBase + (ty << 2) + ii;
    float4 v4 = make_float4(acc[ii][0] * 0.125f, acc[ii][1] * 0.125f,
                            acc[ii][2] * 0.125f, acc[ii][3] * 0.125f);
    *(float4*)&Cp[(size_t)l * S_ + nBase + (tx << 2)] = v4;
  }
}

// ---------------------------------------------------------------------------
// path_mean[i][j] = (1/32) * sum_bh Sc[bh][i][m1] * Sc[bh][m2][j]
//   m1 = (2i+j)/3 ;  m2 = (i+2j)/3   (integer floor div, always in-bounds)
//
// Tiled: 32x32 output tile per block. For i in [i0,i0+32), j in [j0,j0+32):
//   m1 in [c0, c0+31] where c0=(2*i0+j0)/3  -> A-tile = rows i0..i0+31, cols c0..c0+31
//   m2 in [r0, r0+31] where r0=(i0+2*j0)/3  -> B-tile = rows r0..r0+31, cols j0..j0+31
// Both tiles staged coalesced into LDS; the gather becomes LDS reads.
// Cache-side traffic drops ~10x vs the naive scattered version.
// ---------------------------------------------------------------------------
__global__ __launch_bounds__(256)
void path_mean_kernel(const float* __restrict__ Sc, float* __restrict__ pm) {
  __shared__ float As[32][36];   // rows i0.., cols c0_al.. (36 = 32 span + 4 align slack)
  __shared__ float Bs[32][36];   // rows r0.., cols j0..   (pitch 36 breaks bank alignment)

  // bijective XCD swizzle (nwg=1024 divisible by 8): each XCD gets a
  // contiguous 128-block chunk = 4 i0-bands -> A-row reuse lands in same L2.
  const int orig = blockIdx.x;
  const int wgid = (orig & 7) * 128 + (orig >> 3);
  const int i0 = (wgid >> 5) << 5;
  const int j0 = (wgid & 31) << 5;

  const int c0 = (2 * i0 + j0) / 3;
  const int c0_al = c0 & ~3;           // float4-aligned start; c0-c0_al in [0,3]
  const int r0 = (i0 + 2 * j0) / 3;

  const int tid = threadIdx.x;
  const int row_s = tid >> 3;          // 0..31 staging row
  const int c4 = tid & 7;              // 0..7 staging float4 col

  // Output mapping: thread -> (row gi = i0+ti, cols j0+4*tj+b), b=0..3
  const int ti = tid >> 3;             // 0..31
  const int tj = tid & 7;              // 0..7
  const int gi = i0 + ti;

  int aoff[4], boff[4];
#pragma unroll
  for (int b = 0; b < 4; ++b) {
    const int gj = j0 + 4 * tj + b;
    const int m1 = (2 * gi + gj) / 3;
    const int m2 = (gi + 2 * gj) / 3;
    aoff[b] = ti * 36 + (m1 - c0_al);      // in [0, 31*36+34]
    boff[b] = (m2 - r0) * 36 + (4 * tj + b);
  }

  // Staging pointers (z-invariant part). gcA <= 992+28 = 1020, always in-bounds.
  const int gcA = c0_al + 4 * c4;
  int gcA2 = c0_al + 32; if (gcA2 > 1020) gcA2 = 1020;  // clamp only when c0=992 (cols unused then)
  const float* pA  = Sc + (size_t)(i0 + row_s) * S_ + gcA;
  const float* pA2 = Sc + (size_t)(i0 + (tid & 31)) * S_ + gcA2;
  const float* pB  = Sc + (size_t)(r0 + row_s) * S_ + j0 + 4 * c4;
  const float* As0 = &As[0][0];
  const float* Bs0 = &Bs[0][0];

  float acc[4] = {0.f, 0.f, 0.f, 0.f};
  for (int z = 0; z < NBH; ++z) {
    const size_t zo = (size_t)z * (L_ * S_);
    const float4 av = *(const float4*)(pA + zo);
    const float4 bv = *(const float4*)(pB + zo);
    float4 av2;
    if (tid < 32) av2 = *(const float4*)(pA2 + zo);
    __syncthreads();                      // previous iteration's reads done
    *(float4*)&As[row_s][4 * c4] = av;
    if (tid < 32) *(float4*)&As[tid][32] = av2;
    *(float4*)&Bs[row_s][4 * c4] = bv;
    __syncthreads();
#pragma unroll
    for (int b = 0; b < 4; ++b)
      acc[b] = fmaf(As0[aoff[b]], Bs0[boff[b]], acc[b]);
  }
  float4 o = make_float4(acc[0] * (1.f / 32.f), acc[1] * (1.f / 32.f),
                         acc[2] * (1.f / 32.f), acc[3] * (1.f / 32.f));
  *(float4*)&pm[(size_t)gi * S_ + j0 + 4 * tj] = o;
}

// ---------------------------------------------------------------------------
// Masked softmax, in place over the scores region (which becomes attn).
// Row r = (bh, i). val[j] = |i-j|<=3 ? Sc[r][j] : pm[i][j]; softmax over j.
// ---------------------------------------------------------------------------
__global__ __launch_bounds__(256)
void softmax_kernel(float* __restrict__ Sc, const float* __restrict__ pm) {
  const int r = blockIdx.x;            // 0..32767
  const int i = r & 1023;
  float* row = Sc + (size_t)r * S_;
  const float* pmrow = pm + (size_t)i * S_;
  const int tid = threadIdx.x;
  const int j0 = tid << 2;
  const float4 sv = *(const float4*)(row + j0);
  const float4 pv = *(const float4*)(pmrow + j0);
  float vals[4] = {sv.x, sv.y, sv.z, sv.w};
  const float pvals[4] = {pv.x, pv.y, pv.z, pv.w};
  float mx = -1e30f;
#pragma unroll
  for (int u = 0; u < 4; ++u) {
    const int j = j0 + u;
    const int diff = i - j;
    const bool near = (diff <= 3) && (diff >= -3);
    vals[u] = near ? vals[u] : pvals[u];
    mx = fmaxf(mx, vals[u]);
  }
  __shared__ float redm[4];
  __shared__ float reds[4];
  const int lane = tid & 63, wid = tid >> 6;
#pragma unroll
  for (int off = 32; off >= 1; off >>= 1) mx = fmaxf(mx, __shfl_xor(mx, off));
  if (lane == 0) redm[wid] = mx;
  __syncthreads();
  mx = fmaxf(fmaxf(redm[0], redm[1]), fmaxf(redm[2], redm[3]));
  float sum = 0.f;
#pragma unroll
  for (int u = 0; u < 4; ++u) {
    vals[u] = __expf(vals[u] - mx);
    sum += vals[u];
  }
#pragma unroll
  for (int off = 32; off >= 1; off >>= 1) sum += __shfl_xor(sum, off);
  if (lane == 0) reds[wid] = sum;
  __syncthreads();
  sum = reds[0] + reds[1] + reds[2] + reds[3];
  const float inv = 1.f / sum;
  float4 o = make_float4(vals[0] * inv, vals[1] * inv, vals[2] * inv, vals[3] * inv);
  *(float4*)(row + j0) = o;
}

// ---------------------------------------------------------------------------
// PV: per bh, out1[b][l][h*64+d] = sum_s attn[bh][l][s] * v[bh][s][d]
// NN GEMM, BM=64, BN=64(=DH full), BK=16; A transposed into LDS on store.
// ---------------------------------------------------------------------------
__global__ __launch_bounds__(256)
void gemm_pv_kernel(const float* __restrict__ attn, const float* __restrict__ v,
                    float* __restrict__ out1) {
  __shared__ float As[16][68];
  __shared__ float Bs[16][64];
  const int z = blockIdx.z;
  const int bb = z >> 3, hh = z & 7;
  const float* Ap = attn + (size_t)z * L_ * S_;
  const float* Bp = v + (size_t)z * S_ * DH;
  const int tid = threadIdx.x;
  const int tx = tid & 15, ty = tid >> 4;
  const int mBase = blockIdx.y * 64;
  const int arow = tid >> 2;
  const int acol = (tid & 3) << 2;
  const int brow = tid >> 4;
  const int bcol = (tid & 15) << 2;
  float acc[4][4] = {};
  for (int k0 = 0; k0 < S_; k0 += 16) {
    const float4 av = *(const float4*)(Ap + (size_t)(mBase + arow) * S_ + k0 + acol);
    const float4 bv = *(const float4*)(Bp + (size_t)(k0 + brow) * DH + bcol);
    __syncthreads();
    As[acol + 0][arow] = av.x;
    As[acol + 1][arow] = av.y;
    As[acol + 2][arow] = av.z;
    As[acol + 3][arow] = av.w;
    *(float4*)&Bs[brow][bcol] = bv;
    __syncthreads();
#pragma unroll
    for (int kk = 0; kk < 16; ++kk) {
      const float4 a4 = *(const float4*)&As[kk][ty << 2];
      const float4 b4 = *(const float4*)&Bs[kk][tx << 2];
      const float aa[4] = {a4.x, a4.y, a4.z, a4.w};
      const float bb4[4] = {b4.x, b4.y, b4.z, b4.w};
#pragma unroll
      for (int ii = 0; ii < 4; ++ii)
#pragma unroll
        for (int jj = 0; jj < 4; ++jj)
          acc[ii][jj] = fmaf(aa[ii], bb4[jj], acc[ii][jj]);
    }
  }
#pragma unroll
  for (int ii = 0; ii < 4; ++ii) {
    const int l = mBase + (ty << 2) + ii;
    float4 v4 = make_float4(acc[ii][0], acc[ii][1], acc[ii][2], acc[ii][3]);
    *(float4*)&out1[(size_t)(bb * L_ + l) * DMODEL + hh * DH + (tx << 2)] = v4;
  }
}

// ---------------------------------------------------------------------------
extern "C" void kernel_launch(void* const* d_in, const int* in_sizes, int n_in,
                              void* d_out, int out_size, void* d_ws, size_t ws_size,
                              hipStream_t stream) {
  const float* queries = (const float*)d_in[0];
  const float* keys    = (const float*)d_in[1];
  const float* values  = (const float*)d_in[2];
  const float* Wq      = (const float*)d_in[3];
  const float* Wk      = (const float*)d_in[4];
  const float* Wv      = (const float*)d_in[5];
  const float* Wo      = (const float*)d_in[6];

  float* out  = (float*)d_out;                          // (B,L,512)
  float* attn = out + (size_t)B_ * L_ * DMODEL;         // (B,H,L,S) - also scores scratch

  float* ws   = (float*)d_ws;
  float* qT   = ws;                 // (B,H,D,L)  2,097,152 f
  float* kT   = qT + 2097152;       // (B,H,D,S)  2,097,152 f
  float* vS   = kT + 2097152;       // (B,H,S,D)  2,097,152 f
  float* out1 = vS + 2097152;       // (B,L,512)  2,097,152 f
  float* pm   = out1 + 2097152;     // (L,S)      1,048,576 f   total ~36 MB

  const dim3 blk(256);

  // 1) projections
  const dim3 gProj(DMODEL / 64, (B_ * L_) / 64);        // (8, 64)
  hipLaunchKernelGGL((gemm_nn_kernel<0>), gProj, blk, 0, stream,
                     queries, Wq, qT, B_ * L_, DMODEL, DMODEL);
  hipLaunchKernelGGL((gemm_nn_kernel<0>), gProj, blk, 0, stream,
                     keys, Wk, kT, B_ * L_, DMODEL, DMODEL);
  hipLaunchKernelGGL((gemm_nn_kernel<1>), gProj, blk, 0, stream,
                     values, Wv, vS, B_ * L_, DMODEL, DMODEL);

  // 2) scores = q k^T / 8   (written into the attn region of d_out)
  const dim3 gSc(S_ / 64, L_ / 64, NBH);                // (16,16,32)
  hipLaunchKernelGGL(scores_kernel, gSc, blk, 0, stream, qT, kT, attn);

  // 3) path_mean from raw scores (tiled gather)
  const dim3 gPm(1024);
  hipLaunchKernelGGL(path_mean_kernel, gPm, blk, 0, stream, attn, pm);

  // 4) masked softmax in place -> attn
  const dim3 gSm(NBH * L_);                             // 32768 rows
  hipLaunchKernelGGL(softmax_kernel, gSm, blk, 0, stream, attn, pm);

  // 5) PV -> out1 (B,L,512)
  const dim3 gPv(1, L_ / 64, NBH);
  hipLaunchKernelGGL(gemm_pv_kernel, gPv, blk, 0, stream, attn, vS, out1);

  // 6) out = out1 @ W_o
  const dim3 gO(DMODEL / 64, (B_ * L_) / 64);
  hipLaunchKernelGGL((gemm_nn_kernel<2>), gO, blk, 0, stream,
                     out1, Wo, out, B_ * L_, DMODEL, DMODEL);
}

// Round 3
// 224.599 us; speedup vs baseline: 1.9752x; 1.6304x over previous
//
#include <hip/hip_runtime.h>
#include <math.h>

static constexpr int B_ = 4;
static constexpr int L_ = 1024;
static constexpr int S_ = 1024;
static constexpr int DMODEL = 512;
static constexpr int NH = 8;
static constexpr int DH = 64;
static constexpr int NBH = 32;   // B_*NH

typedef __attribute__((ext_vector_type(8))) short s8;      // 8 bf16 (4 VGPRs)
typedef __attribute__((ext_vector_type(4))) float floatx4; // MFMA accumulator

__device__ __forceinline__ short f2bf(float f) {           // RNE f32->bf16
  unsigned u = __float_as_uint(f);
  return (short)((u + 0x7fffu + ((u >> 16) & 1u)) >> 16);
}
__device__ __forceinline__ float bf2f(short s) {
  return __uint_as_float(((unsigned)(unsigned short)s) << 16);
}

// ---------------------------------------------------------------------------
// Convert queries/keys/values (f32) -> contiguous bf16 segments in ws.
// 3 * 2,097,152 floats; 8 per thread.
// ---------------------------------------------------------------------------
__global__ __launch_bounds__(256)
void cvt_inputs_kernel(const float* __restrict__ q, const float* __restrict__ k,
                       const float* __restrict__ v, short* __restrict__ dst) {
  const int i = blockIdx.x * 256 + threadIdx.x;          // 0..786431
  const int arr = i >> 18;                               // 0..2 (uniform per block)
  const int off = (i & 262143) << 3;
  const float* src = (arr == 0) ? q : (arr == 1) ? k : v;
  const float4 f0 = *(const float4*)(src + off);
  const float4 f1 = *(const float4*)(src + off + 4);
  s8 o;
  o[0] = f2bf(f0.x); o[1] = f2bf(f0.y); o[2] = f2bf(f0.z); o[3] = f2bf(f0.w);
  o[4] = f2bf(f1.x); o[5] = f2bf(f1.y); o[6] = f2bf(f1.z); o[7] = f2bf(f1.w);
  *(s8*)(dst + (size_t)arr * 2097152 + off) = o;
}

// ---------------------------------------------------------------------------
// Transpose + cvt the 4 weight matrices: W (512x512 f32, [k][n]) -> WT bf16 [n][k]
// ---------------------------------------------------------------------------
__global__ __launch_bounds__(256)
void wtrans_kernel(const float* __restrict__ Wq, const float* __restrict__ Wk,
                   const float* __restrict__ Wv, const float* __restrict__ Wo,
                   short* __restrict__ WT) {
  __shared__ float t[32][33];
  const int z = blockIdx.z;
  const float* W = (z == 0) ? Wq : (z == 1) ? Wk : (z == 2) ? Wv : Wo;
  short* dst = WT + (size_t)z * 262144;
  const int k0 = blockIdx.y * 32, n0 = blockIdx.x * 32;
  const int row = threadIdx.x >> 3;          // 0..31
  const int c4 = (threadIdx.x & 7) << 2;     // 0,4,..28
  const float4 f = *(const float4*)(W + (size_t)(k0 + row) * 512 + n0 + c4);
  t[row][c4 + 0] = f.x; t[row][c4 + 1] = f.y; t[row][c4 + 2] = f.z; t[row][c4 + 3] = f.w;
  __syncthreads();
#pragma unroll
  for (int j = 0; j < 4; ++j)
    dst[(size_t)(n0 + row) * 512 + k0 + c4 + j] = f2bf(t[c4 + j][row]);
}

// ---------------------------------------------------------------------------
// MFMA projection GEMM: C = A(M x K, bf16 row-major) @ WT^T (WT is N x K bf16).
// 64x64 tile / block, 4 waves (2x2 of 32x32), 2x2 fragments of 16x16x32.
// Fragments loaded directly from global (8 contiguous k per lane).
// MODE 0: store bf16 (B,H,L,D)   MODE 1: store bf16 (B,H,D,S)   MODE 2: f32 row-major
// ---------------------------------------------------------------------------
template<int MODE>
__global__ __launch_bounds__(256)
void proj_mfma_kernel(const short* __restrict__ A, const short* __restrict__ WT,
                      void* __restrict__ C, int K) {
  const int tid = threadIdx.x;
  const int lane = tid & 63, w = tid >> 6;
  const int wm = w >> 1, wn = w & 1;
  const int m0 = blockIdx.y * 64, n0 = blockIdx.x * 64;
  const int kl = (lane >> 4) << 3;            // 0,8,16,24
  const int rA = m0 + wm * 32 + (lane & 15);
  const int rB = n0 + wn * 32 + (lane & 15);
  const short* pA = A + (size_t)rA * K + kl;
  const short* pB = WT + (size_t)rB * K + kl;
  const size_t f16K = (size_t)16 * K;
  floatx4 acc00 = {0,0,0,0}, acc01 = {0,0,0,0}, acc10 = {0,0,0,0}, acc11 = {0,0,0,0};
  for (int k = 0; k < K; k += 32) {
    const s8 a0 = *(const s8*)(pA + k);
    const s8 a1 = *(const s8*)(pA + f16K + k);
    const s8 b0 = *(const s8*)(pB + k);
    const s8 b1 = *(const s8*)(pB + f16K + k);
    acc00 = __builtin_amdgcn_mfma_f32_16x16x32_bf16(a0, b0, acc00, 0, 0, 0);
    acc01 = __builtin_amdgcn_mfma_f32_16x16x32_bf16(a0, b1, acc01, 0, 0, 0);
    acc10 = __builtin_amdgcn_mfma_f32_16x16x32_bf16(a1, b0, acc10, 0, 0, 0);
    acc11 = __builtin_amdgcn_mfma_f32_16x16x32_bf16(a1, b1, acc11, 0, 0, 0);
  }
  const int crow = (lane >> 4) << 2;          // 0,4,8,12
  const int ccol = lane & 15;
#pragma unroll
  for (int fm = 0; fm < 2; ++fm)
#pragma unroll
    for (int fn = 0; fn < 2; ++fn) {
      const floatx4 acc = (fm == 0) ? ((fn == 0) ? acc00 : acc01)
                                    : ((fn == 0) ? acc10 : acc11);
      const int col = n0 + wn * 32 + fn * 16 + ccol;
#pragma unroll
      for (int r = 0; r < 4; ++r) {
        const int row = m0 + wm * 32 + fm * 16 + crow + r;
        if (MODE == 0) {
          const int b = row >> 10, l = row & 1023, h = col >> 6, d = col & 63;
          ((short*)C)[((size_t)((b * NH + h) * L_ + l)) * DH + d] = f2bf(acc[r]);
        } else if (MODE == 1) {
          const int b = row >> 10, s = row & 1023, h = col >> 6, d = col & 63;
          ((short*)C)[((size_t)((b * NH + h) * DH + d)) * S_ + s] = f2bf(acc[r]);
        } else {
          ((float*)C)[(size_t)row * DMODEL + col] = acc[r];
        }
      }
    }
}

// ---------------------------------------------------------------------------
// Scores via MFMA: Sc[bh][l][s] = 0.125 * sum_d q[bh,l,d] * k[bh,s,d]  (f32 out)
// q,k bf16 (B,H,L,D). 64x64 tile, K=64 (2 k-steps). Fragments direct-from-global.
// ---------------------------------------------------------------------------
__global__ __launch_bounds__(256)
void scores_mfma_kernel(const short* __restrict__ qbf, const short* __restrict__ kbf,
                        float* __restrict__ Sc) {
  const int tid = threadIdx.x;
  const int lane = tid & 63, w = tid >> 6;
  const int wm = w >> 1, wn = w & 1;
  const int m0 = blockIdx.y * 64, n0 = blockIdx.x * 64;
  const int bh = blockIdx.z;
  const int kl = (lane >> 4) << 3;
  const short* pA = qbf + (size_t)bh * L_ * DH + (size_t)(m0 + wm * 32 + (lane & 15)) * DH + kl;
  const short* pB = kbf + (size_t)bh * S_ * DH + (size_t)(n0 + wn * 32 + (lane & 15)) * DH + kl;
  floatx4 acc00 = {0,0,0,0}, acc01 = {0,0,0,0}, acc10 = {0,0,0,0}, acc11 = {0,0,0,0};
#pragma unroll
  for (int k = 0; k < DH; k += 32) {
    const s8 a0 = *(const s8*)(pA + k);
    const s8 a1 = *(const s8*)(pA + 16 * DH + k);
    const s8 b0 = *(const s8*)(pB + k);
    const s8 b1 = *(const s8*)(pB + 16 * DH + k);
    acc00 = __builtin_amdgcn_mfma_f32_16x16x32_bf16(a0, b0, acc00, 0, 0, 0);
    acc01 = __builtin_amdgcn_mfma_f32_16x16x32_bf16(a0, b1, acc01, 0, 0, 0);
    acc10 = __builtin_amdgcn_mfma_f32_16x16x32_bf16(a1, b0, acc10, 0, 0, 0);
    acc11 = __builtin_amdgcn_mfma_f32_16x16x32_bf16(a1, b1, acc11, 0, 0, 0);
  }
  float* Cp = Sc + (size_t)bh * L_ * S_;
  const int crow = (lane >> 4) << 2;
  const int ccol = lane & 15;
#pragma unroll
  for (int fm = 0; fm < 2; ++fm)
#pragma unroll
    for (int fn = 0; fn < 2; ++fn) {
      const floatx4 acc = (fm == 0) ? ((fn == 0) ? acc00 : acc01)
                                    : ((fn == 0) ? acc10 : acc11);
      const int col = n0 + wn * 32 + fn * 16 + ccol;
#pragma unroll
      for (int r = 0; r < 4; ++r) {
        const int row = m0 + wm * 32 + fm * 16 + crow + r;
        Cp[(size_t)row * S_ + col] = acc[r] * 0.125f;
      }
    }
}

// ---------------------------------------------------------------------------
// path_mean[i][j] = (1/32) * sum_bh Sc[bh][i][m1] * Sc[bh][m2][j]
// (unchanged from round 2 — tiled gather through LDS)
// ---------------------------------------------------------------------------
__global__ __launch_bounds__(256)
void path_mean_kernel(const float* __restrict__ Sc, float* __restrict__ pm) {
  __shared__ float As[32][36];
  __shared__ float Bs[32][36];
  const int orig = blockIdx.x;
  const int wgid = (orig & 7) * 128 + (orig >> 3);
  const int i0 = (wgid >> 5) << 5;
  const int j0 = (wgid & 31) << 5;
  const int c0 = (2 * i0 + j0) / 3;
  const int c0_al = c0 & ~3;
  const int r0 = (i0 + 2 * j0) / 3;
  const int tid = threadIdx.x;
  const int row_s = tid >> 3;
  const int c4 = tid & 7;
  const int ti = tid >> 3;
  const int tj = tid & 7;
  const int gi = i0 + ti;
  int aoff[4], boff[4];
#pragma unroll
  for (int b = 0; b < 4; ++b) {
    const int gj = j0 + 4 * tj + b;
    const int m1 = (2 * gi + gj) / 3;
    const int m2 = (gi + 2 * gj) / 3;
    aoff[b] = ti * 36 + (m1 - c0_al);
    boff[b] = (m2 - r0) * 36 + (4 * tj + b);
  }
  const int gcA = c0_al + 4 * c4;
  int gcA2 = c0_al + 32; if (gcA2 > 1020) gcA2 = 1020;
  const float* pA  = Sc + (size_t)(i0 + row_s) * S_ + gcA;
  const float* pA2 = Sc + (size_t)(i0 + (tid & 31)) * S_ + gcA2;
  const float* pB  = Sc + (size_t)(r0 + row_s) * S_ + j0 + 4 * c4;
  const float* As0 = &As[0][0];
  const float* Bs0 = &Bs[0][0];
  float acc[4] = {0.f, 0.f, 0.f, 0.f};
  for (int z = 0; z < NBH; ++z) {
    const size_t zo = (size_t)z * (L_ * S_);
    const float4 av = *(const float4*)(pA + zo);
    const float4 bv = *(const float4*)(pB + zo);
    float4 av2;
    if (tid < 32) av2 = *(const float4*)(pA2 + zo);
    __syncthreads();
    *(float4*)&As[row_s][4 * c4] = av;
    if (tid < 32) *(float4*)&As[tid][32] = av2;
    *(float4*)&Bs[row_s][4 * c4] = bv;
    __syncthreads();
#pragma unroll
    for (int b = 0; b < 4; ++b)
      acc[b] = fmaf(As0[aoff[b]], Bs0[boff[b]], acc[b]);
  }
  float4 o = make_float4(acc[0] * (1.f / 32.f), acc[1] * (1.f / 32.f),
                         acc[2] * (1.f / 32.f), acc[3] * (1.f / 32.f));
  *(float4*)&pm[(size_t)gi * S_ + j0 + 4 * tj] = o;
}

// ---------------------------------------------------------------------------
// Masked softmax in place (scores region of d_out becomes attn). Unchanged.
// ---------------------------------------------------------------------------
__global__ __launch_bounds__(256)
void softmax_kernel(float* __restrict__ Sc, const float* __restrict__ pm) {
  const int r = blockIdx.x;
  const int i = r & 1023;
  float* row = Sc + (size_t)r * S_;
  const float* pmrow = pm + (size_t)i * S_;
  const int tid = threadIdx.x;
  const int j0 = tid << 2;
  const float4 sv = *(const float4*)(row + j0);
  const float4 pv = *(const float4*)(pmrow + j0);
  float vals[4] = {sv.x, sv.y, sv.z, sv.w};
  const float pvals[4] = {pv.x, pv.y, pv.z, pv.w};
  float mx = -1e30f;
#pragma unroll
  for (int u = 0; u < 4; ++u) {
    const int j = j0 + u;
    const int diff = i - j;
    const bool near = (diff <= 3) && (diff >= -3);
    vals[u] = near ? vals[u] : pvals[u];
    mx = fmaxf(mx, vals[u]);
  }
  __shared__ float redm[4];
  __shared__ float reds[4];
  const int lane = tid & 63, wid = tid >> 6;
#pragma unroll
  for (int off = 32; off >= 1; off >>= 1) mx = fmaxf(mx, __shfl_xor(mx, off));
  if (lane == 0) redm[wid] = mx;
  __syncthreads();
  mx = fmaxf(fmaxf(redm[0], redm[1]), fmaxf(redm[2], redm[3]));
  float sum = 0.f;
#pragma unroll
  for (int u = 0; u < 4; ++u) {
    vals[u] = __expf(vals[u] - mx);
    sum += vals[u];
  }
#pragma unroll
  for (int off = 32; off >= 1; off >>= 1) sum += __shfl_xor(sum, off);
  if (lane == 0) reds[wid] = sum;
  __syncthreads();
  sum = reds[0] + reds[1] + reds[2] + reds[3];
  const float inv = 1.f / sum;
  float4 o = make_float4(vals[0] * inv, vals[1] * inv, vals[2] * inv, vals[3] * inv);
  *(float4*)(row + j0) = o;
}

// ---------------------------------------------------------------------------
// PV via MFMA: out1[b,l,h*64+d] (bf16) = sum_s attn[bh,l,s] * v[bh,s,d]
// A = attn f32 (cvt to bf16 in-register), B = vT bf16 (B,H,D,S).
// 64(l) x 64(d) tile per block, grid (16 l-tiles, 32 bh). K = 1024.
// ---------------------------------------------------------------------------
__global__ __launch_bounds__(256)
void pv_mfma_kernel(const float* __restrict__ attn, const short* __restrict__ vT,
                    short* __restrict__ out1) {
  const int tid = threadIdx.x;
  const int lane = tid & 63, w = tid >> 6;
  const int wm = w >> 1, wn = w & 1;
  const int m0 = blockIdx.x * 64;
  const int bh = blockIdx.y;
  const int b = bh >> 3, h = bh & 7;
  const int kl = (lane >> 4) << 3;
  const float* pA = attn + (size_t)bh * L_ * S_ + (size_t)(m0 + wm * 32 + (lane & 15)) * S_ + kl;
  const short* pB = vT + (size_t)bh * DH * S_ + (size_t)(wn * 32 + (lane & 15)) * S_ + kl;
  floatx4 acc00 = {0,0,0,0}, acc01 = {0,0,0,0}, acc10 = {0,0,0,0}, acc11 = {0,0,0,0};
  for (int k = 0; k < S_; k += 32) {
    const float4 fa0 = *(const float4*)(pA + k);
    const float4 fa1 = *(const float4*)(pA + k + 4);
    const float4 fb0 = *(const float4*)(pA + 16 * S_ + k);
    const float4 fb1 = *(const float4*)(pA + 16 * S_ + k + 4);
    s8 a0, a1;
    a0[0] = f2bf(fa0.x); a0[1] = f2bf(fa0.y); a0[2] = f2bf(fa0.z); a0[3] = f2bf(fa0.w);
    a0[4] = f2bf(fa1.x); a0[5] = f2bf(fa1.y); a0[6] = f2bf(fa1.z); a0[7] = f2bf(fa1.w);
    a1[0] = f2bf(fb0.x); a1[1] = f2bf(fb0.y); a1[2] = f2bf(fb0.z); a1[3] = f2bf(fb0.w);
    a1[4] = f2bf(fb1.x); a1[5] = f2bf(fb1.y); a1[6] = f2bf(fb1.z); a1[7] = f2bf(fb1.w);
    const s8 b0 = *(const s8*)(pB + k);
    const s8 b1 = *(const s8*)(pB + 16 * S_ + k);
    acc00 = __builtin_amdgcn_mfma_f32_16x16x32_bf16(a0, b0, acc00, 0, 0, 0);
    acc01 = __builtin_amdgcn_mfma_f32_16x16x32_bf16(a0, b1, acc01, 0, 0, 0);
    acc10 = __builtin_amdgcn_mfma_f32_16x16x32_bf16(a1, b0, acc10, 0, 0, 0);
    acc11 = __builtin_amdgcn_mfma_f32_16x16x32_bf16(a1, b1, acc11, 0, 0, 0);
  }
  const int crow = (lane >> 4) << 2;
  const int ccol = lane & 15;
#pragma unroll
  for (int fm = 0; fm < 2; ++fm)
#pragma unroll
    for (int fn = 0; fn < 2; ++fn) {
      const floatx4 acc = (fm == 0) ? ((fn == 0) ? acc00 : acc01)
                                    : ((fn == 0) ? acc10 : acc11);
      const int d = wn * 32 + fn * 16 + ccol;
#pragma unroll
      for (int r = 0; r < 4; ++r) {
        const int l = m0 + wm * 32 + fm * 16 + crow + r;
        out1[((size_t)(b * L_ + l)) * DMODEL + h * DH + d] = f2bf(acc[r]);
      }
    }
}

// ---------------------------------------------------------------------------
extern "C" void kernel_launch(void* const* d_in, const int* in_sizes, int n_in,
                              void* d_out, int out_size, void* d_ws, size_t ws_size,
                              hipStream_t stream) {
  const float* queries = (const float*)d_in[0];
  const float* keys    = (const float*)d_in[1];
  const float* values  = (const float*)d_in[2];
  const float* Wq      = (const float*)d_in[3];
  const float* Wk      = (const float*)d_in[4];
  const float* Wv      = (const float*)d_in[5];
  const float* Wo      = (const float*)d_in[6];

  float* out  = (float*)d_out;                          // (B,L,512) f32
  float* attn = out + (size_t)B_ * L_ * DMODEL;         // (B,H,L,S) f32 (scores->attn)

  char* ws = (char*)d_ws;
  short* xbf  = (short*)(ws);                    // 3 x 2,097,152 bf16 (q,k,v inputs)
  short* WT   = (short*)(ws + 12u * 1048576);    // 4 x 262,144 bf16 (Wq,Wk,Wv,Wo)^T
  short* qbf  = (short*)(ws + 14u * 1048576);    // (B,H,L,D) bf16
  short* kbf  = (short*)(ws + 18u * 1048576);    // (B,H,S,D) bf16
  short* vT   = (short*)(ws + 22u * 1048576);    // (B,H,D,S) bf16
  float* pm   = (float*)(ws + 26u * 1048576);    // (L,S) f32
  short* out1 = (short*)(ws + 30u * 1048576);    // (B,L,512) bf16   total 34 MB

  const dim3 blk(256);

  // 0) input f32->bf16, weight transpose->bf16
  hipLaunchKernelGGL(cvt_inputs_kernel, dim3(3072), blk, 0, stream,
                     queries, keys, values, xbf);
  hipLaunchKernelGGL(wtrans_kernel, dim3(16, 16, 4), blk, 0, stream,
                     Wq, Wk, Wv, Wo, WT);

  // 1) projections (MFMA): q,k -> (B,H,L,D); v -> (B,H,D,S)
  const dim3 gProj(DMODEL / 64, (B_ * L_) / 64);        // (8, 64)
  hipLaunchKernelGGL((proj_mfma_kernel<0>), gProj, blk, 0, stream,
                     xbf,            WT,               (void*)qbf, DMODEL);
  hipLaunchKernelGGL((proj_mfma_kernel<0>), gProj, blk, 0, stream,
                     xbf + 2097152,  WT + 262144,      (void*)kbf, DMODEL);
  hipLaunchKernelGGL((proj_mfma_kernel<1>), gProj, blk, 0, stream,
                     xbf + 4194304,  WT + 524288,      (void*)vT,  DMODEL);

  // 2) scores = q k^T / 8 (f32, into attn region)
  const dim3 gSc(S_ / 64, L_ / 64, NBH);                // (16,16,32)
  hipLaunchKernelGGL(scores_mfma_kernel, gSc, blk, 0, stream, qbf, kbf, attn);

  // 3) path_mean from raw scores (tiled gather)
  hipLaunchKernelGGL(path_mean_kernel, dim3(1024), blk, 0, stream, attn, pm);

  // 4) masked softmax in place -> attn
  hipLaunchKernelGGL(softmax_kernel, dim3(NBH * L_), blk, 0, stream, attn, pm);

  // 5) PV (MFMA) -> out1 bf16 (B,L,512)
  hipLaunchKernelGGL(pv_mfma_kernel, dim3(L_ / 64, NBH), blk, 0, stream,
                     attn, vT, out1);

  // 6) out = out1 @ W_o (MFMA, f32 out)
  hipLaunchKernelGGL((proj_mfma_kernel<2>), gProj, blk, 0, stream,
                     out1, WT + 786432, (void*)out, DMODEL);
}